// Round 3
// baseline (351.685 us; speedup 1.0000x reference)
//
#include <hip/hip_runtime.h>
#include <hip/hip_bf16.h>
#include <stdint.h>
#include <stddef.h>

typedef __bf16 bf16_t;
typedef __bf16 bf16x8 __attribute__((ext_vector_type(8)));
typedef float f32x16 __attribute__((ext_vector_type(16)));

#define B_DIM 8192
#define K_DIM 4096
#define N_DIM 4096

typedef __attribute__((address_space(1))) const void gvoid_t;
typedef __attribute__((address_space(3))) void lvoid_t;

__device__ __forceinline__ void gload_lds16(const void* g, void* l) {
  // width-16 global->LDS DMA; LDS dest is wave-uniform base + lane*16
  __builtin_amdgcn_global_load_lds((gvoid_t*)g, (lvoid_t*)l, 16, 0, 0);
}

#define FENCE() asm volatile("" ::: "memory")
#define BARRIER() do { FENCE(); __builtin_amdgcn_s_barrier(); FENCE(); } while (0)

// ------- kernel 1 (merged prep): row L2-norm+cvt for x, cvt for W -------
__global__ __launch_bounds__(256) void prep_kernel(
    const float* __restrict__ x, const float* __restrict__ W,
    bf16_t* __restrict__ xb, bf16_t* __restrict__ Wb) {
  const int t = threadIdx.x;
  if (blockIdx.x < B_DIM) {
    const int row = blockIdx.x;
    const float4* xr = (const float4*)(x + (size_t)row * K_DIM);
    float4 v[4];
    float ss = 0.f;
#pragma unroll
    for (int i = 0; i < 4; ++i) {
      v[i] = xr[i * 256 + t];
      ss += v[i].x * v[i].x + v[i].y * v[i].y + v[i].z * v[i].z + v[i].w * v[i].w;
    }
#pragma unroll
    for (int o = 32; o > 0; o >>= 1) ss += __shfl_down(ss, o, 64);
    __shared__ float wsum[4];
    __shared__ float s_scale;
    const int lane = t & 63, wv = t >> 6;
    if (lane == 0) wsum[wv] = ss;
    __syncthreads();
    if (t == 0) {
      float s = wsum[0] + wsum[1] + wsum[2] + wsum[3];
      s_scale = 1.0f / (sqrtf(s) + 1e-4f);
    }
    __syncthreads();
    const float sc = s_scale;
    bf16_t* orow = xb + (size_t)row * K_DIM;
#pragma unroll
    for (int i = 0; i < 4; ++i) {
      union { bf16_t h[4]; uint2 u; } p;
      p.h[0] = (bf16_t)(v[i].x * sc);
      p.h[1] = (bf16_t)(v[i].y * sc);
      p.h[2] = (bf16_t)(v[i].z * sc);
      p.h[3] = (bf16_t)(v[i].w * sc);
      ((uint2*)orow)[i * 256 + t] = p.u;
    }
  } else {
    const size_t idx = (size_t)(blockIdx.x - B_DIM) * 256 + t;  // one float4 each
    float4 a = ((const float4*)W)[idx];
    union { bf16_t h[4]; uint2 u; } p;
    p.h[0] = (bf16_t)a.x;
    p.h[1] = (bf16_t)a.y;
    p.h[2] = (bf16_t)a.z;
    p.h[3] = (bf16_t)a.w;
    ((uint2*)Wb)[idx] = p.u;
  }
}

// ---------------- kernel 2: 256x256 8-phase GEMM, C = A @ W^T + bias, ReLU --
// A: 8192x4096 bf16 rm; Bm: 4096x4096 bf16 rm (both K-major). BK=64.
// 8 waves (2M x 4N), per-wave 128x64 out = 4x2 subtiles of 32x32 (mfma 32x32x16).
// LDS 128 KiB: [buf(2)][mat(A,B)][half(2)][128 rows][64 cols] bf16,
// XOR-swizzled: byte ^= (row&7)<<4 (linear DMA dest + pre-swizzled gsrc).
__global__ __launch_bounds__(512, 1) void gemm_kernel(
    const bf16_t* __restrict__ A, const bf16_t* __restrict__ Bm,
    const float* __restrict__ bias, float* __restrict__ C) {
  __shared__ __align__(16) char lds[131072];
  const int tid = threadIdx.x;
  const int lane = tid & 63, w = tid >> 6;
  const int wm = w >> 2, wn = w & 3;
  const int l31 = lane & 31;    // row/col within 32x32 fragment
  const int khi = lane >> 5;    // k-half selector

  // XCD-contiguous swizzle (512 blocks, 512 % 8 == 0 -> bijective)
  const int bid = blockIdx.x;
  const int sid = (bid & 7) * 64 + (bid >> 3);
  const int mb = sid & 31;      // 32 M-tiles
  const int nb = sid >> 5;      // 16 N-tiles

  const char* Ag = (const char*)(A + (size_t)mb * 256 * K_DIM);
  const char* Bg = (const char*)(Bm + (size_t)nb * 256 * K_DIM);

  // stage half-tile (mat 0=A,1=B; half h) of K-tile kt: 2 x gload_lds16/thread
  auto STAGE = [&](int mat, int h, int kt) {
    const int rbase = (kt & 1) * 65536 + mat * 32768 + h * 16384;
    const char* gb = (mat == 0 ? Ag : Bg) + (size_t)h * 128 * (K_DIM * 2) + kt * 128;
#pragma unroll
    for (int i = 0; i < 2; ++i) {
      const int qb = i * 8192 + w * 1024;          // wave-uniform LDS offset
      const int q = qb + lane * 16;                // this lane's linear slot
      const int r = q >> 7;                        // logical row (swizzle keeps row)
      const int cb = (q & 127) ^ ((r & 7) << 4);   // inverse-swizzled col byte
      gload_lds16(gb + (size_t)r * (K_DIM * 2) + cb, lds + rbase + qb);
    }
  };
  // 32x32x16 fragments: lane holds row/col (lane&31), 8 contiguous k at
  // k-byte = ks*32 + (lane>>5)*16 (A and B identical -> k-perm cancels)
  auto LDA32 = [&](int ms, int ks, int cur) -> bf16x8 {
    const int r = ms * 32 + l31;
    const int q = (r << 7) + ks * 32 + khi * 16;
    return *(const bf16x8*)(lds + cur * 65536 + wm * 16384 + (q ^ ((r & 7) << 4)));
  };
  auto LDB32 = [&](int ns, int ks, int cur) -> bf16x8 {
    const int r = (wn & 1) * 64 + ns * 32 + l31;
    const int q = (r << 7) + ks * 32 + khi * 16;
    return *(const bf16x8*)(lds + cur * 65536 + 32768 + (wn >> 1) * 16384 + (q ^ ((r & 7) << 4)));
  };

  f32x16 acc[4][2] = {};
  bf16x8 af[2][4], bfr[2][4];

  // prologue: A(T0).h0,h1  B(T0).h0,h1  B(T1).h0,h1 ; leave B(T1) in flight
  STAGE(0, 0, 0); STAGE(0, 1, 0); STAGE(1, 0, 0); STAGE(1, 1, 0);
  STAGE(1, 0, 1); STAGE(1, 1, 1);
  asm volatile("s_waitcnt vmcnt(4)" ::: "memory");
  BARRIER();

  for (int u = 0; u < 64; ++u) {
    const int cur = u & 1;
    const int un1 = (u + 1) & 63, un2 = (u + 2) & 63;  // wrap keeps parity, dead data
    // ---- P1: read A ms0-1 + B ns0; stage A(T_{u+1}).h0; MFMA Q00
#pragma unroll
    for (int ks = 0; ks < 4; ++ks) bfr[0][ks] = LDB32(0, ks, cur);
#pragma unroll
    for (int ms = 0; ms < 2; ++ms)
#pragma unroll
      for (int ks = 0; ks < 4; ++ks) af[ms][ks] = LDA32(ms, ks, cur);
    STAGE(0, 0, un1);
    BARRIER();
    __builtin_amdgcn_s_setprio(1);
#pragma unroll
    for (int ms = 0; ms < 2; ++ms)
#pragma unroll
      for (int ks = 0; ks < 4; ++ks)
        acc[ms][0] = __builtin_amdgcn_mfma_f32_32x32x16_bf16(af[ms][ks], bfr[0][ks], acc[ms][0], 0, 0, 0);
    __builtin_amdgcn_s_setprio(0);
    BARRIER();
    // ---- P2: read B ns1; stage A(T_{u+1}).h1; MFMA Q01
#pragma unroll
    for (int ks = 0; ks < 4; ++ks) bfr[1][ks] = LDB32(1, ks, cur);
    STAGE(0, 1, un1);
    BARRIER();
    __builtin_amdgcn_s_setprio(1);
#pragma unroll
    for (int ms = 0; ms < 2; ++ms)
#pragma unroll
      for (int ks = 0; ks < 4; ++ks)
        acc[ms][1] = __builtin_amdgcn_mfma_f32_32x32x16_bf16(af[ms][ks], bfr[1][ks], acc[ms][1], 0, 0, 0);
    __builtin_amdgcn_s_setprio(0);
    BARRIER();
    // ---- P3: read A ms2-3 (overwrite af); stage B(T_{u+2}).h0; MFMA Q10
#pragma unroll
    for (int ms = 0; ms < 2; ++ms)
#pragma unroll
      for (int ks = 0; ks < 4; ++ks) af[ms][ks] = LDA32(ms + 2, ks, cur);
    STAGE(1, 0, un2);
    BARRIER();
    __builtin_amdgcn_s_setprio(1);
#pragma unroll
    for (int ms = 0; ms < 2; ++ms)
#pragma unroll
      for (int ks = 0; ks < 4; ++ks)
        acc[ms + 2][0] = __builtin_amdgcn_mfma_f32_32x32x16_bf16(af[ms][ks], bfr[0][ks], acc[ms + 2][0], 0, 0, 0);
    __builtin_amdgcn_s_setprio(0);
    BARRIER();
    // ---- P4: stage B(T_{u+2}).h1; MFMA Q11; counted gate vmcnt(4)
    STAGE(1, 1, un2);
    BARRIER();
    __builtin_amdgcn_s_setprio(1);
#pragma unroll
    for (int ms = 0; ms < 2; ++ms)
#pragma unroll
      for (int ks = 0; ks < 4; ++ks)
        acc[ms + 2][1] = __builtin_amdgcn_mfma_f32_32x32x16_bf16(af[ms][ks], bfr[1][ks], acc[ms + 2][1], 0, 0, 0);
    __builtin_amdgcn_s_setprio(0);
    asm volatile("s_waitcnt vmcnt(4)" ::: "memory");  // leave B(T_{u+2}) in flight only
    BARRIER();
  }

  // epilogue: bias + ReLU, fp32 store.
  // 32x32 C/D map (m74/m101): col=lane&31, row=(reg&3)+8*(reg>>2)+4*(lane>>5)
  float bv[2];
#pragma unroll
  for (int ns = 0; ns < 2; ++ns) bv[ns] = bias[nb * 256 + wn * 64 + ns * 32 + l31];
#pragma unroll
  for (int ms = 0; ms < 4; ++ms) {
    const int row0 = mb * 256 + wm * 128 + ms * 32 + khi * 4;
    const int col0 = nb * 256 + wn * 64 + l31;
#pragma unroll
    for (int rg = 0; rg < 4; ++rg)
#pragma unroll
      for (int j = 0; j < 4; ++j) {
        float* crow = C + (size_t)(row0 + rg * 8 + j) * N_DIM + col0;
#pragma unroll
        for (int ns = 0; ns < 2; ++ns)
          crow[ns * 32] = fmaxf(acc[ms][ns][rg * 4 + j] + bv[ns], 0.f);
      }
  }
}

extern "C" void kernel_launch(void* const* d_in, const int* in_sizes, int n_in,
                              void* d_out, int out_size, void* d_ws, size_t ws_size,
                              hipStream_t stream) {
  const float* x = (const float*)d_in[0];
  const float* W = (const float*)d_in[1];
  const float* b = (const float*)d_in[2];
  float* out = (float*)d_out;

  bf16_t* xb = (bf16_t*)d_ws;                       // 8192*4096*2 = 64 MB
  bf16_t* Wb = xb + (size_t)B_DIM * K_DIM;          // 4096*4096*2 = 32 MB

  // 8192 norm blocks + 16384 W-convert blocks in one dispatch
  prep_kernel<<<B_DIM + (N_DIM * (size_t)K_DIM) / 4 / 256, 256, 0, stream>>>(x, W, xb, Wb);
  gemm_kernel<<<32 * 16, 512, 0, stream>>>(xb, Wb, b, out);
}

// Round 4
// 313.099 us; speedup vs baseline: 1.1232x; 1.1232x over previous
//
#include <hip/hip_runtime.h>
#include <hip/hip_bf16.h>
#include <stdint.h>
#include <stddef.h>

typedef __bf16 bf16_t;
typedef __bf16 bf16x8 __attribute__((ext_vector_type(8)));
typedef float f32x4 __attribute__((ext_vector_type(4)));

#define B_DIM 8192
#define K_DIM 4096
#define N_DIM 4096

typedef __attribute__((address_space(1))) const void gvoid_t;
typedef __attribute__((address_space(3))) void lvoid_t;

__device__ __forceinline__ void gload_lds16(const void* g, void* l) {
  // width-16 global->LDS DMA; LDS dest is wave-uniform base + lane*16
  __builtin_amdgcn_global_load_lds((gvoid_t*)g, (lvoid_t*)l, 16, 0, 0);
}

#define FENCE() asm volatile("" ::: "memory")
#define BARRIER() do { FENCE(); __builtin_amdgcn_s_barrier(); FENCE(); } while (0)

// ------- kernel 1 (merged prep): row L2-norm+cvt for x, cvt for W -------
__global__ __launch_bounds__(256) void prep_kernel(
    const float* __restrict__ x, const float* __restrict__ W,
    bf16_t* __restrict__ xb, bf16_t* __restrict__ Wb) {
  const int t = threadIdx.x;
  if (blockIdx.x < B_DIM) {
    const int row = blockIdx.x;
    const float4* xr = (const float4*)(x + (size_t)row * K_DIM);
    float4 v[4];
    float ss = 0.f;
#pragma unroll
    for (int i = 0; i < 4; ++i) {
      v[i] = xr[i * 256 + t];
      ss += v[i].x * v[i].x + v[i].y * v[i].y + v[i].z * v[i].z + v[i].w * v[i].w;
    }
#pragma unroll
    for (int o = 32; o > 0; o >>= 1) ss += __shfl_down(ss, o, 64);
    __shared__ float wsum[4];
    __shared__ float s_scale;
    const int lane = t & 63, wv = t >> 6;
    if (lane == 0) wsum[wv] = ss;
    __syncthreads();
    if (t == 0) {
      float s = wsum[0] + wsum[1] + wsum[2] + wsum[3];
      s_scale = 1.0f / (sqrtf(s) + 1e-4f);
    }
    __syncthreads();
    const float sc = s_scale;
    bf16_t* orow = xb + (size_t)row * K_DIM;
#pragma unroll
    for (int i = 0; i < 4; ++i) {
      union { bf16_t h[4]; uint2 u; } p;
      p.h[0] = (bf16_t)(v[i].x * sc);
      p.h[1] = (bf16_t)(v[i].y * sc);
      p.h[2] = (bf16_t)(v[i].z * sc);
      p.h[3] = (bf16_t)(v[i].w * sc);
      ((uint2*)orow)[i * 256 + t] = p.u;
    }
  } else {
    const size_t idx = (size_t)(blockIdx.x - B_DIM) * 256 + t;  // one float4 each
    float4 a = ((const float4*)W)[idx];
    union { bf16_t h[4]; uint2 u; } p;
    p.h[0] = (bf16_t)a.x;
    p.h[1] = (bf16_t)a.y;
    p.h[2] = (bf16_t)a.z;
    p.h[3] = (bf16_t)a.w;
    ((uint2*)Wb)[idx] = p.u;
  }
}

// ---------------- kernel 2: 256x256 8-phase GEMM, C = A @ W^T + bias, ReLU --
// A: 8192x4096 bf16 rm; Bm: 4096x4096 bf16 rm (both K-major). BK=64.
// 8 waves (2M x 4N), per-wave 128x64 out = 8x4 frags of 16x16 (mfma 16x16x32 —
// 32x32x16 regressed: 32-row column reads defeat the 8-slot XOR swizzle, R3).
// LDS 128 KiB: [buf(2)][mat(A,B)][half(2)][128 rows][64 cols] bf16,
// XOR-swizzled: byte ^= (row&7)<<4 (linear DMA dest + pre-swizzled gsrc).
__global__ __launch_bounds__(512, 1) void gemm_kernel(
    const bf16_t* __restrict__ A, const bf16_t* __restrict__ Bm,
    const float* __restrict__ bias, float* __restrict__ C) {
  __shared__ __align__(16) char lds[131072];
  const int tid = threadIdx.x;
  const int lane = tid & 63, w = tid >> 6;
  const int wm = w >> 2, wn = w & 3;
  const int hi16 = lane >> 4;   // 0..3 (k-slot)
  const int r16 = lane & 15;

  // XCD-contiguous swizzle (512 blocks, 512 % 8 == 0 -> bijective)
  const int bid = blockIdx.x;
  const int sid = (bid & 7) * 64 + (bid >> 3);
  const int mb = sid & 31;      // 32 M-tiles
  const int nb = sid >> 5;      // 16 N-tiles (64 consecutive sids share 2 B-panels)

  const char* Ag = (const char*)(A + (size_t)mb * 256 * K_DIM);
  const char* Bg = (const char*)(Bm + (size_t)nb * 256 * K_DIM);

  // stage half-tile (mat 0=A,1=B; half h) of K-tile kt: 2 x gload_lds16/thread
  auto STAGE = [&](int mat, int h, int kt) {
    const int rbase = (kt & 1) * 65536 + mat * 32768 + h * 16384;
    const char* gb = (mat == 0 ? Ag : Bg) + (size_t)h * 128 * (K_DIM * 2) + kt * 128;
#pragma unroll
    for (int i = 0; i < 2; ++i) {
      const int qb = i * 8192 + w * 1024;          // wave-uniform LDS offset
      const int q = qb + lane * 16;                // this lane's linear slot
      const int r = q >> 7;                        // logical row (swizzle keeps row)
      const int cb = (q & 127) ^ ((r & 7) << 4);   // inverse-swizzled col byte
      gload_lds16(gb + (size_t)r * (K_DIM * 2) + cb, lds + rbase + qb);
    }
  };
  auto LDA = [&](int m, int kq, int cur) -> bf16x8 {
    const int r = m * 16 + r16;
    const int q = (r << 7) + (kq << 6) + hi16 * 16;
    return *(const bf16x8*)(lds + cur * 65536 + wm * 16384 + (q ^ ((r & 7) << 4)));
  };
  auto LDB = [&](int n, int kq, int cur) -> bf16x8 {
    const int r = (wn & 1) * 64 + n * 16 + r16;
    const int q = (r << 7) + (kq << 6) + hi16 * 16;
    return *(const bf16x8*)(lds + cur * 65536 + 32768 + (wn >> 1) * 16384 + (q ^ ((r & 7) << 4)));
  };

  f32x4 acc[8][4] = {};
  bf16x8 af[4][2], bfr[4][2];

  // prologue: A(T0).h0,h1  B(T0).h0,h1  B(T1).h0,h1 ; leave B(T1) in flight
  STAGE(0, 0, 0); STAGE(0, 1, 0); STAGE(1, 0, 0); STAGE(1, 1, 0);
  STAGE(1, 0, 1); STAGE(1, 1, 1);
  asm volatile("s_waitcnt vmcnt(4)" ::: "memory");
  BARRIER();

  for (int u = 0; u < 64; ++u) {
    const int cur = u & 1;
    const int un1 = (u + 1) & 63, un2 = (u + 2) & 63;  // wrap keeps parity, dead data
    // ---- P1: read bfr[0-1], af[0-3], bfr[2-3]; stage A(T_{u+1}).h0; MFMA Q00
#pragma unroll
    for (int n = 0; n < 2; ++n)
#pragma unroll
      for (int kq = 0; kq < 2; ++kq) bfr[n][kq] = LDB(n, kq, cur);
#pragma unroll
    for (int m = 0; m < 4; ++m)
#pragma unroll
      for (int kq = 0; kq < 2; ++kq) af[m][kq] = LDA(m, kq, cur);
#pragma unroll
    for (int n = 2; n < 4; ++n)
#pragma unroll
      for (int kq = 0; kq < 2; ++kq) bfr[n][kq] = LDB(n, kq, cur);
    STAGE(0, 0, un1);
    BARRIER();
    __builtin_amdgcn_s_setprio(1);
#pragma unroll
    for (int m = 0; m < 4; ++m)
#pragma unroll
      for (int n = 0; n < 2; ++n)
#pragma unroll
        for (int kq = 0; kq < 2; ++kq)
          acc[m][n] = __builtin_amdgcn_mfma_f32_16x16x32_bf16(af[m][kq], bfr[n][kq], acc[m][n], 0, 0, 0);
    __builtin_amdgcn_s_setprio(0);
    BARRIER();
    // ---- P2: stage A(T_{u+1}).h1; MFMA Q01 (operands already in regs)
    STAGE(0, 1, un1);
    BARRIER();
    __builtin_amdgcn_s_setprio(1);
#pragma unroll
    for (int m = 0; m < 4; ++m)
#pragma unroll
      for (int n = 2; n < 4; ++n)
#pragma unroll
        for (int kq = 0; kq < 2; ++kq)
          acc[m][n] = __builtin_amdgcn_mfma_f32_16x16x32_bf16(af[m][kq], bfr[n][kq], acc[m][n], 0, 0, 0);
    __builtin_amdgcn_s_setprio(0);
    BARRIER();
    // ---- P3: read A m4-7 (overwrite af); stage B(T_{u+2}).h0; MFMA Q10
#pragma unroll
    for (int m = 0; m < 4; ++m)
#pragma unroll
      for (int kq = 0; kq < 2; ++kq) af[m][kq] = LDA(m + 4, kq, cur);
    STAGE(1, 0, un2);
    BARRIER();
    __builtin_amdgcn_s_setprio(1);
#pragma unroll
    for (int m = 0; m < 4; ++m)
#pragma unroll
      for (int n = 0; n < 2; ++n)
#pragma unroll
        for (int kq = 0; kq < 2; ++kq)
          acc[m + 4][n] = __builtin_amdgcn_mfma_f32_16x16x32_bf16(af[m][kq], bfr[n][kq], acc[m + 4][n], 0, 0, 0);
    __builtin_amdgcn_s_setprio(0);
    BARRIER();
    // ---- P4: stage B(T_{u+2}).h1; MFMA Q11; counted gate vmcnt(4)
    STAGE(1, 1, un2);
    BARRIER();
    __builtin_amdgcn_s_setprio(1);
#pragma unroll
    for (int m = 0; m < 4; ++m)
#pragma unroll
      for (int n = 2; n < 4; ++n)
#pragma unroll
        for (int kq = 0; kq < 2; ++kq)
          acc[m + 4][n] = __builtin_amdgcn_mfma_f32_16x16x32_bf16(af[m][kq], bfr[n][kq], acc[m + 4][n], 0, 0, 0);
    __builtin_amdgcn_s_setprio(0);
    asm volatile("s_waitcnt vmcnt(4)" ::: "memory");  // leave B(T_{u+2}) in flight only
    BARRIER();
  }

  // epilogue: bias + ReLU, fp32 store. C/D map: col=lane&15, row=(lane>>4)*4+j
  float bv[4];
#pragma unroll
  for (int n = 0; n < 4; ++n) bv[n] = bias[nb * 256 + wn * 64 + n * 16 + r16];
#pragma unroll
  for (int m = 0; m < 8; ++m) {
    const int row0 = mb * 256 + wm * 128 + m * 16 + hi16 * 4;
#pragma unroll
    for (int j = 0; j < 4; ++j) {
      float* crow = C + (size_t)(row0 + j) * N_DIM + nb * 256 + wn * 64 + r16;
#pragma unroll
      for (int n = 0; n < 4; ++n)
        crow[n * 16] = fmaxf(acc[m][n][j] + bv[n], 0.f);
    }
  }
}

extern "C" void kernel_launch(void* const* d_in, const int* in_sizes, int n_in,
                              void* d_out, int out_size, void* d_ws, size_t ws_size,
                              hipStream_t stream) {
  const float* x = (const float*)d_in[0];
  const float* W = (const float*)d_in[1];
  const float* b = (const float*)d_in[2];
  float* out = (float*)d_out;

  bf16_t* xb = (bf16_t*)d_ws;                       // 8192*4096*2 = 64 MB
  bf16_t* Wb = xb + (size_t)B_DIM * K_DIM;          // 4096*4096*2 = 32 MB

  // 8192 norm blocks + 16384 W-convert blocks in one dispatch
  prep_kernel<<<B_DIM + (N_DIM * (size_t)K_DIM) / 4 / 256, 256, 0, stream>>>(x, W, xb, Wb);
  gemm_kernel<<<32 * 16, 512, 0, stream>>>(xb, Wb, b, out);
}